// Round 13
// baseline (1408.355 us; speedup 1.0000x reference)
//
#include <hip/hip_runtime.h>
#include <cstdint>
#include <cstddef>

#define HD 128
#define EMBD 96
#define SELD 32
#define PD 64
#define NPOS 513
#define GITERS 6
#define SROW 136

typedef _Float16 f16;
typedef __attribute__((ext_vector_type(8))) _Float16 f16x8;
typedef __attribute__((ext_vector_type(4))) _Float16 f16x4;
typedef __attribute__((ext_vector_type(2))) _Float16 f16x2;
typedef __attribute__((ext_vector_type(4))) float f32x4;

__device__ __forceinline__ float sigm(float x) {
    return __builtin_amdgcn_rcpf(1.0f + __expf(-x));
}
__device__ __forceinline__ float tanh_f(float x) {
    return 2.0f * __builtin_amdgcn_rcpf(1.0f + __expf(-2.0f * x)) - 1.0f;
}

// ---------------- setup kernels ----------------

__global__ void k_deg(const int* __restrict__ ei, const int* __restrict__ et,
                      int* __restrict__ cnt_t, int E, int N) {
    int e = blockIdx.x * 256 + threadIdx.x;
    if (e < E) {
        int d = ei[E + e];
        atomicAdd(&cnt_t[(size_t)et[e] * N + d], 1);
    }
}

__launch_bounds__(1024)
__global__ void k_scan1(const int* __restrict__ cnt_t, int* __restrict__ rp,
                        int* __restrict__ bsum, int N) {
    __shared__ int sc[1024];
    int t = threadIdx.x;
    int i = blockIdx.x * 1024 + t;
    int v = 0;
    if (i < N)
        v = cnt_t[i] + cnt_t[(size_t)N + i] + cnt_t[2 * (size_t)N + i];
    sc[t] = v;
    __syncthreads();
    for (int off = 1; off < 1024; off <<= 1) {
        int u = (t >= off) ? sc[t - off] : 0;
        __syncthreads();
        sc[t] += u;
        __syncthreads();
    }
    if (i < N) rp[i] = sc[t] - v;
    if (t == 1023) bsum[blockIdx.x] = sc[t];
}

__launch_bounds__(1024)
__global__ void k_scan2(int* __restrict__ bsum, int nb) {
    __shared__ int sc[1024];
    int t = threadIdx.x;
    int v = (t < nb) ? bsum[t] : 0;
    sc[t] = v;
    __syncthreads();
    for (int off = 1; off < 1024; off <<= 1) {
        int u = (t >= off) ? sc[t - off] : 0;
        __syncthreads();
        sc[t] += u;
        __syncthreads();
    }
    if (t < nb) bsum[t] = sc[t] - v;
}

__global__ void k_scan3(const int* __restrict__ rp, const int* __restrict__ bsum,
                        const int* __restrict__ cnt_t, float4* __restrict__ cntp,
                        int4* __restrict__ rp4, int N) {
    int i = blockIdx.x * 256 + threadIdx.x;
    if (i < N) {
        int start = rp[i] + bsum[i >> 10];
        int c0 = cnt_t[i];
        int c1 = cnt_t[(size_t)N + i];
        int c2 = cnt_t[2 * (size_t)N + i];
        rp4[i] = make_int4(start, start + c0, start + c0 + c1, start + c0 + c1 + c2);
        float4 v;
        v.x = (float)c0; v.y = (float)c1; v.z = (float)c2;
        v.w = 1.0f / fmaxf((float)(c0 + c1 + c2), 1.0f);
        cntp[i] = v;
    }
}

__global__ void k_fill(const int* __restrict__ ei, const int* __restrict__ et,
                       const int* __restrict__ ep, const int4* __restrict__ rp4,
                       int* __restrict__ cur3, int2* __restrict__ e2, int E, int N) {
    int e = blockIdx.x * 256 + threadIdx.x;
    if (e < E) {
        int d = ei[E + e];
        int t = et[e];
        int4 r4 = rp4[d];
        int base = (t == 0) ? r4.x : ((t == 1) ? r4.y : r4.z);
        int pos = atomicAdd(&cur3[(size_t)t * N + d], 1);
        e2[base + pos] = make_int2(ei[e], ep[e]);
    }
}

__global__ void k_gate(const float* __restrict__ pe, const float* __restrict__ Wg,
                       const float* __restrict__ bg, f16* __restrict__ gb) {
    int p = blockIdx.x;
    int j = threadIdx.x;
    float acc = bg[j];
    #pragma unroll 8
    for (int k = 0; k < PD; ++k) acc += pe[p * PD + k] * Wg[k * HD + j];
    gb[p * HD + j] = (f16)(2.0f * sigm(acc));
}

__global__ void k_prep(const float* __restrict__ Wt, const float* __restrict__ W1,
                       f16* __restrict__ WtT, f16* __restrict__ W1T) {
    const int SZ = 3 * HD * HD;
    int id = blockIdx.x * 256 + threadIdx.x;
    if (id < SZ) {
        int t = id / (HD * HD), rem = id % (HD * HD);
        int n = rem / HD, k = rem % HD;
        WtT[id] = (f16)Wt[t * HD * HD + k * HD + n];
    } else if (id < SZ + 2 * HD * HD) {
        int rem = id - SZ;
        int n = rem / (2 * HD), k = rem % (2 * HD);
        W1T[rem] = (f16)W1[k * HD + n];
    }
}

// Wcat [512 rows j][256 k]
__global__ void k_prepW(const float* __restrict__ Wih, const float* __restrict__ Whh,
                        f16* __restrict__ Wcat) {
    int id = blockIdx.x * 256 + threadIdx.x;
    if (id < 512 * 256) {
        int j = id >> 8, k = id & 255;
        float v;
        if (j < 256)      v = (k < 128) ? Wih[j * 128 + k] : Whh[j * 128 + (k - 128)];
        else if (j < 384) v = (k < 128) ? Wih[j * 128 + k] : 0.0f;
        else              v = (k < 128) ? 0.0f : Whh[(j - 128) * 128 + (k - 128)];
        Wcat[id] = (f16)v;
    }
}

__global__ void k_init(const int* __restrict__ xidx, const float* __restrict__ sel,
                       const float* __restrict__ emb, f16* __restrict__ h, int N) {
    int id = blockIdx.x * 256 + threadIdx.x;
    if (id < N * HD) {
        int n = id >> 7, j = id & 127;
        float v = (j < EMBD) ? emb[(size_t)xidx[n] * EMBD + j]
                             : sel[(size_t)n * SELD + (j - EMBD)];
        h[id] = (f16)v;
    }
}

// ---------------- fused per-iteration kernel ----------------
// 32 rows/block, 512 thr (8 waves).
// P1: quad-row gather (lane quarter qw owns row wave+qw*8, f16x8 16B loads),
//     type-sorted CSR + prefix-subtract packed-f16 accumulation -> S.
// P2: message MFMA (wave = 2 row-tiles x 4 col-groups, 24 MFMAs) -> agg regs
//     -> aggL written into S[0] region (reuse).
// P3: GRU GEMM from LDS [aggL|hL] (wave = col-group, 48 MFMAs, Wcat once/blk)
//     + fast GRU epilogue -> hOut in S -> coalesced h_out store.
__launch_bounds__(512, 4)
__global__ void k_iter(const int4* __restrict__ rp4, const int2* __restrict__ e2,
                       const f16* __restrict__ h_in, const f16* __restrict__ gb,
                       const f16* __restrict__ WtT, const float* __restrict__ bt,
                       const float4* __restrict__ cntp, const f16* __restrict__ Wcat,
                       const float* __restrict__ bih, const float* __restrict__ bhh,
                       f16* __restrict__ h_out, int N) {
    __shared__ f16 S[3 * 32 * SROW];   // 26.1 KB; S[0..32*SROW) reused as aggL, then hOut
    __shared__ f16 hL[32 * SROW];      //  8.7 KB

    int tid = threadIdx.x;
    int wave = tid >> 6, lane = tid & 63;
    int quad = lane >> 4, m = lane & 15;
    int d0 = blockIdx.x * 32;

    // ---- stage hL: thread t -> row t>>4, chunk t&15 (f16x8)
    {
        int row = tid >> 4, ch = tid & 15;
        int grow = min(d0 + row, N - 1);
        f16x8 v = *(const f16x8*)(h_in + (size_t)grow * HD + ch * 8);
        *(f16x8*)(hL + row * SROW + ch * 8) = v;
    }

    // ---- P1: quad-row gather
    {
        int qw = lane >> 4, ql = lane & 15;
        int lrow = wave + qw * 8;
        int grow = d0 + lrow;
        bool valid = grow < N;
        int4 r4 = rp4[min(grow, N - 1)];
        int es = r4.x, b1 = r4.y, b2 = r4.z, ee = r4.w;
        if (!valid) ee = es;
        int dg = ee - es;
        int t1 = max(dg, __shfl_xor(dg, 16));
        int t2 = max(t1, __shfl_xor(t1, 32));
        int nb = (__builtin_amdgcn_readfirstlane(t2) + 7) >> 3;
        int co = ql * 8;  // 8 f16 per lane (16 B)

        const f16x8 zf = {0, 0, 0, 0, 0, 0, 0, 0};
        f16x8 accA = zf, accB = zf, accC = zf;
        for (int b = 0; b < nb; ++b) {
            int e0 = es + b * 8;
            int2 ev[8];
            #pragma unroll
            for (int j = 0; j < 8; ++j) {
                int idx = max(min(e0 + j, ee - 1), 0);
                ev[j] = e2[idx];
            }
            f16x8 hv[8], gv[8];
            #pragma unroll
            for (int j = 0; j < 8; ++j) {
                hv[j] = *(const f16x8*)(h_in + (size_t)ev[j].x * HD + co);
                gv[j] = *(const f16x8*)(gb + (size_t)ev[j].y * HD + co);
            }
            #pragma unroll
            for (int j = 0; j < 8; ++j) {
                int eidx = e0 + j;
                f16x8 g0 = (eidx < ee) ? gv[j] : zf;   // active mask
                accA += hv[j] * g0;
                f16x8 gB = (eidx >= b1) ? g0 : zf;
                accB += hv[j] * gB;
                f16x8 gC = (eidx >= b2) ? g0 : zf;
                accC += hv[j] * gC;
            }
        }
        f16x8 s0 = accA - accB;   // type-0 sum
        f16x8 s1 = accB - accC;   // type-1 sum
        *(f16x8*)(S + (0 * 32 + lrow) * SROW + co) = s0;
        *(f16x8*)(S + (1 * 32 + lrow) * SROW + co) = s1;
        *(f16x8*)(S + (2 * 32 + lrow) * SROW + co) = accC;
    }
    __syncthreads();

    // ---- P2: message MFMA. wave = (tau = wave&1, cgp = wave>>1)
    float aggv[2][4];
    {
        int tau = wave & 1, cgp = wave >> 1;
        #pragma unroll
        for (int s = 0; s < 2; ++s) {
            int col = cgp * 32 + s * 16 + m;
            f32x4 acc = {0.f, 0.f, 0.f, 0.f};
            #pragma unroll
            for (int t = 0; t < 3; ++t)
                #pragma unroll
                for (int c = 0; c < 4; ++c) {
                    f16x8 a = *(const f16x8*)(S + (t * 32 + tau * 16 + m) * SROW + c * 32 + quad * 8);
                    f16x8 b = *(const f16x8*)(WtT + ((size_t)t * HD + col) * HD + c * 32 + quad * 8);
                    acc = __builtin_amdgcn_mfma_f32_16x16x32_f16(a, b, acc, 0, 0, 0);
                }
            float bt0 = bt[col], bt1 = bt[HD + col], bt2 = bt[2 * HD + col];
            #pragma unroll
            for (int r = 0; r < 4; ++r) {
                int lr = tau * 16 + quad * 4 + r;
                int dd = min(d0 + lr, N - 1);
                float4 cp = cntp[dd];
                aggv[s][r] = (acc[r] + cp.x * bt0 + cp.y * bt1 + cp.z * bt2) * cp.w;
            }
        }
    }
    __syncthreads();  // all S reads done

    // ---- write aggL into S[0] region
    {
        int tau = wave & 1, cgp = wave >> 1;
        #pragma unroll
        for (int s = 0; s < 2; ++s)
            #pragma unroll
            for (int r = 0; r < 4; ++r)
                S[(tau * 16 + quad * 4 + r) * SROW + cgp * 32 + s * 16 + m] = (f16)aggv[s][r];
    }
    __syncthreads();

    // ---- P3: GRU GEMM. wave = col-group jg; j = jg*16+m; tau2 in {0,1}
    {
        int j = wave * 16 + m;
        f32x4 ar[2], az[2], an[2], ah[2];
        const f32x4 z4 = {0.f, 0.f, 0.f, 0.f};
        #pragma unroll
        for (int t2 = 0; t2 < 2; ++t2) { ar[t2] = z4; az[t2] = z4; an[t2] = z4; ah[t2] = z4; }

        #pragma unroll
        for (int c = 0; c < 8; ++c) {
            f16x8 br = *(const f16x8*)(Wcat + (size_t)j * 256 + c * 32 + quad * 8);
            f16x8 bz = *(const f16x8*)(Wcat + (size_t)(128 + j) * 256 + c * 32 + quad * 8);
            f16x8 bn = (c < 4)
                ? *(const f16x8*)(Wcat + (size_t)(256 + j) * 256 + c * 32 + quad * 8)
                : *(const f16x8*)(Wcat + (size_t)(384 + j) * 256 + c * 32 + quad * 8);
            #pragma unroll
            for (int t2 = 0; t2 < 2; ++t2) {
                f16x8 a = (c < 4)
                    ? *(const f16x8*)(S + (t2 * 16 + m) * SROW + c * 32 + quad * 8)
                    : *(const f16x8*)(hL + (t2 * 16 + m) * SROW + (c - 4) * 32 + quad * 8);
                ar[t2] = __builtin_amdgcn_mfma_f32_16x16x32_f16(a, br, ar[t2], 0, 0, 0);
                az[t2] = __builtin_amdgcn_mfma_f32_16x16x32_f16(a, bz, az[t2], 0, 0, 0);
                if (c < 4) an[t2] = __builtin_amdgcn_mfma_f32_16x16x32_f16(a, bn, an[t2], 0, 0, 0);
                else       ah[t2] = __builtin_amdgcn_mfma_f32_16x16x32_f16(a, bn, ah[t2], 0, 0, 0);
            }
        }

        float b_r  = bih[j] + bhh[j];
        float b_z  = bih[HD + j] + bhh[HD + j];
        float b_in = bih[2 * HD + j];
        float b_hn = bhh[2 * HD + j];
        float hp[2][4];
        #pragma unroll
        for (int t2 = 0; t2 < 2; ++t2)
            #pragma unroll
            for (int r = 0; r < 4; ++r) {
                int row = t2 * 16 + quad * 4 + r;
                float hval = (float)hL[row * SROW + j];
                float rr = sigm(ar[t2][r] + b_r);
                float zz = sigm(az[t2][r] + b_z);
                float nn = tanh_f(an[t2][r] + b_in + rr * (ah[t2][r] + b_hn));
                hp[t2][r] = (1.0f - zz) * nn + zz * hval;
            }
        __syncthreads();  // all aggL/hL reads done before hOut overwrite

        #pragma unroll
        for (int t2 = 0; t2 < 2; ++t2)
            #pragma unroll
            for (int r = 0; r < 4; ++r)
                S[(t2 * 16 + quad * 4 + r) * SROW + j] = (f16)hp[t2][r];
    }
    __syncthreads();

    // ---- coalesced copy-out: thread t -> row t>>4, chunk t&15
    {
        int row = tid >> 4, ch = tid & 15;
        if (d0 + row < N) {
            f16x8 v = *(const f16x8*)(S + row * SROW + ch * 8);
            *(f16x8*)(h_out + (size_t)(d0 + row) * HD + ch * 8) = v;
        }
    }
}

// feats=[h|emb[x]|sel] (f16 frags) @ W1T (MFMA) -> relu -> @W2 + b2
__launch_bounds__(256)
__global__ void k_final(const f16* __restrict__ h_f, const int* __restrict__ xidx,
                        const float* __restrict__ sel, const float* __restrict__ emb,
                        const f16* __restrict__ W1T, const float* __restrict__ b1,
                        const float* __restrict__ W2, const float* __restrict__ b2,
                        float* __restrict__ out, int N) {
    __shared__ float red[4][16];
    int tid = threadIdx.x;
    int wave = tid >> 6, lane = tid & 63;
    int quad = lane >> 4, m = lane & 15;
    int row0 = blockIdx.x * 16;
    int arow = min(row0 + m, N - 1);
    int xi = xidx[arow];

    f16x8 fa[8];
    #pragma unroll
    for (int c = 0; c < 4; ++c)
        fa[c] = *(const f16x8*)(h_f + (size_t)arow * HD + c * 32 + quad * 8);
    #pragma unroll
    for (int c = 4; c < 7; ++c) {
        const float* ep = emb + (size_t)xi * EMBD + (c - 4) * 32 + quad * 8;
        #pragma unroll
        for (int jj = 0; jj < 8; ++jj) fa[c][jj] = (f16)ep[jj];
    }
    {
        const float* sp = sel + (size_t)arow * SELD + quad * 8;
        #pragma unroll
        for (int jj = 0; jj < 8; ++jj) fa[7][jj] = (f16)sp[jj];
    }

    f32x4 acc[2];
    const f32x4 z4 = {0.f, 0.f, 0.f, 0.f};
    acc[0] = z4; acc[1] = z4;
    #pragma unroll
    for (int s = 0; s < 2; ++s) {
        int c0 = (wave * 2 + s) * 16;
        #pragma unroll
        for (int c = 0; c < 8; ++c) {
            f16x8 b = *(const f16x8*)(W1T + (size_t)(c0 + m) * (2 * HD) + c * 32 + quad * 8);
            acc[s] = __builtin_amdgcn_mfma_f32_16x16x32_f16(fa[c], b, acc[s], 0, 0, 0);
        }
    }

    float psum[4] = {0.f, 0.f, 0.f, 0.f};
    #pragma unroll
    for (int s = 0; s < 2; ++s) {
        int col = (wave * 2 + s) * 16 + m;
        float b1v = b1[col], w2v = W2[col];
        #pragma unroll
        for (int r = 0; r < 4; ++r)
            psum[r] += fmaxf(acc[s][r] + b1v, 0.0f) * w2v;
    }
    #pragma unroll
    for (int off = 1; off < 16; off <<= 1)
        #pragma unroll
        for (int r = 0; r < 4; ++r) psum[r] += __shfl_xor(psum[r], off);

    if (m == 0) {
        #pragma unroll
        for (int r = 0; r < 4; ++r) red[wave][quad * 4 + r] = psum[r];
    }
    __syncthreads();
    if (tid < 16) {
        int row = row0 + tid;
        if (row < N) out[row] = red[0][tid] + red[1][tid] + red[2][tid] + red[3][tid] + b2[0];
    }
}

// ---------------- launcher ----------------

extern "C" void kernel_launch(void* const* d_in, const int* in_sizes, int n_in,
                              void* d_out, int out_size, void* d_ws, size_t ws_size,
                              hipStream_t stream) {
    const int*   xidx = (const int*)d_in[0];
    const float* sel  = (const float*)d_in[1];
    const int*   ei   = (const int*)d_in[2];
    const int*   et   = (const int*)d_in[3];
    const int*   ep   = (const int*)d_in[4];
    const float* emb  = (const float*)d_in[5];
    const float* pe   = (const float*)d_in[6];
    const float* Wg   = (const float*)d_in[7];
    const float* bg   = (const float*)d_in[8];
    const float* Wt   = (const float*)d_in[9];
    const float* bt   = (const float*)d_in[10];
    const float* Wih  = (const float*)d_in[11];
    const float* Whh  = (const float*)d_in[12];
    const float* bih  = (const float*)d_in[13];
    const float* bhh  = (const float*)d_in[14];
    const float* W1   = (const float*)d_in[15];
    const float* b1   = (const float*)d_in[16];
    const float* W2   = (const float*)d_in[17];
    const float* b2   = (const float*)d_in[18];

    const int N = in_sizes[0];
    const int E = in_sizes[3];
    const size_t NH = (size_t)N * HD;

    char* p = (char*)d_ws;
    f16*    hbf0  = (f16*)p;    p += NH * 2;
    f16*    hbf1  = (f16*)p;    p += NH * 2;
    f16*    gb    = (f16*)p;    p += (size_t)NPOS * HD * 2;
    f16*    WtT   = (f16*)p;    p += 3 * HD * HD * 2;
    f16*    Wcat  = (f16*)p;    p += 512 * 256 * 2;
    f16*    W1T   = (f16*)p;    p += 2 * HD * HD * 2;
    float4* cntp  = (float4*)p; p += (size_t)N * 16;
    int4*   rp4   = (int4*)p;   p += (size_t)N * 16;
    int* cnt_t  = (int*)p; p += 3 * (size_t)N * 4;
    int* rp     = (int*)p; p += (size_t)N * 4;
    int* cur3   = (int*)p; p += 3 * (size_t)N * 4;
    int* bsum   = (int*)p; p += 1024 * 4;
    int2* e2    = (int2*)p;

    // ---- setup ----
    hipMemsetAsync(cnt_t, 0, 3 * (size_t)N * sizeof(int), stream);
    hipMemsetAsync(cur3, 0, 3 * (size_t)N * sizeof(int), stream);
    k_deg<<<(E + 255) / 256, 256, 0, stream>>>(ei, et, cnt_t, E, N);
    const int nb1 = (N + 1023) / 1024;
    k_scan1<<<nb1, 1024, 0, stream>>>(cnt_t, rp, bsum, N);
    k_scan2<<<1, 1024, 0, stream>>>(bsum, nb1);
    k_scan3<<<(N + 255) / 256, 256, 0, stream>>>(rp, bsum, cnt_t, cntp, rp4, N);
    k_fill<<<(E + 255) / 256, 256, 0, stream>>>(ei, et, ep, rp4, cur3, e2, E, N);
    k_gate<<<NPOS, HD, 0, stream>>>(pe, Wg, bg, gb);
    k_prep<<<(3 * HD * HD + 2 * HD * HD + 255) / 256, 256, 0, stream>>>(Wt, W1, WtT, W1T);
    k_prepW<<<512, 256, 0, stream>>>(Wih, Whh, Wcat);
    k_init<<<(N * HD + 255) / 256, 256, 0, stream>>>(xidx, sel, emb, hbf0, N);

    const int gI = (N + 31) / 32;
    const f16* hin = hbf0;
    f16* hout = hbf1;
    for (int it = 0; it < GITERS; ++it) {
        k_iter<<<gI, 512, 0, stream>>>(rp4, e2, hin, gb, WtT, bt, cntp, Wcat,
                                       bih, bhh, hout, N);
        const f16* tmp = hout;
        hout = (f16*)hin;
        hin = tmp;
    }

    const int gF = (N + 15) / 16;
    k_final<<<gF, 256, 0, stream>>>(hin, xidx, sel, emb, W1T, b1, W2, b2, (float*)d_out, N);
}

// Round 14
// 1314.413 us; speedup vs baseline: 1.0715x; 1.0715x over previous
//
#include <hip/hip_runtime.h>
#include <cstdint>
#include <cstddef>

#define HD 128
#define EMBD 96
#define SELD 32
#define PD 64
#define NPOS 513
#define GITERS 6

typedef _Float16 f16;
typedef __attribute__((ext_vector_type(8))) _Float16 f16x8;
typedef __attribute__((ext_vector_type(4))) _Float16 f16x4;
typedef __attribute__((ext_vector_type(2))) _Float16 f16x2;
typedef __attribute__((ext_vector_type(4))) float f32x4;

__device__ __forceinline__ float sigm(float x) {
    return __builtin_amdgcn_rcpf(1.0f + __expf(-x));
}
__device__ __forceinline__ float tanh_f(float x) {
    return 2.0f * __builtin_amdgcn_rcpf(1.0f + __expf(-2.0f * x)) - 1.0f;
}

// ---------------- setup kernels ----------------

__global__ void k_deg(const int* __restrict__ ei, const int* __restrict__ et,
                      int* __restrict__ cnt_t, int E, int N) {
    int e = blockIdx.x * 256 + threadIdx.x;
    if (e < E) {
        int d = ei[E + e];
        atomicAdd(&cnt_t[(size_t)et[e] * N + d], 1);
    }
}

__launch_bounds__(1024)
__global__ void k_scan1(const int* __restrict__ cnt_t, int* __restrict__ rp,
                        int* __restrict__ bsum, int N) {
    __shared__ int sc[1024];
    int t = threadIdx.x;
    int i = blockIdx.x * 1024 + t;
    int v = 0;
    if (i < N)
        v = cnt_t[i] + cnt_t[(size_t)N + i] + cnt_t[2 * (size_t)N + i];
    sc[t] = v;
    __syncthreads();
    for (int off = 1; off < 1024; off <<= 1) {
        int u = (t >= off) ? sc[t - off] : 0;
        __syncthreads();
        sc[t] += u;
        __syncthreads();
    }
    if (i < N) rp[i] = sc[t] - v;
    if (t == 1023) bsum[blockIdx.x] = sc[t];
}

__launch_bounds__(1024)
__global__ void k_scan2(int* __restrict__ bsum, int nb) {
    __shared__ int sc[1024];
    int t = threadIdx.x;
    int v = (t < nb) ? bsum[t] : 0;
    sc[t] = v;
    __syncthreads();
    for (int off = 1; off < 1024; off <<= 1) {
        int u = (t >= off) ? sc[t - off] : 0;
        __syncthreads();
        sc[t] += u;
        __syncthreads();
    }
    if (t < nb) bsum[t] = sc[t] - v;
}

__global__ void k_scan3(const int* __restrict__ rp, const int* __restrict__ bsum,
                        const int* __restrict__ cnt_t, float4* __restrict__ cntp,
                        int4* __restrict__ rp4, int N) {
    int i = blockIdx.x * 256 + threadIdx.x;
    if (i < N) {
        int start = rp[i] + bsum[i >> 10];
        int c0 = cnt_t[i];
        int c1 = cnt_t[(size_t)N + i];
        int c2 = cnt_t[2 * (size_t)N + i];
        rp4[i] = make_int4(start, start + c0, start + c0 + c1, start + c0 + c1 + c2);
        float4 v;
        v.x = (float)c0; v.y = (float)c1; v.z = (float)c2;
        v.w = 1.0f / fmaxf((float)(c0 + c1 + c2), 1.0f);
        cntp[i] = v;
    }
}

__global__ void k_fill(const int* __restrict__ ei, const int* __restrict__ et,
                       const int* __restrict__ ep, const int4* __restrict__ rp4,
                       int* __restrict__ cur3, int2* __restrict__ e2, int E, int N) {
    int e = blockIdx.x * 256 + threadIdx.x;
    if (e < E) {
        int d = ei[E + e];
        int t = et[e];
        int4 r4 = rp4[d];
        int base = (t == 0) ? r4.x : ((t == 1) ? r4.y : r4.z);
        int pos = atomicAdd(&cur3[(size_t)t * N + d], 1);
        e2[base + pos] = make_int2(ei[e], ep[e]);
    }
}

__global__ void k_gate(const float* __restrict__ pe, const float* __restrict__ Wg,
                       const float* __restrict__ bg, f16* __restrict__ gb) {
    int p = blockIdx.x;
    int j = threadIdx.x;
    float acc = bg[j];
    #pragma unroll 8
    for (int k = 0; k < PD; ++k) acc += pe[p * PD + k] * Wg[k * HD + j];
    gb[p * HD + j] = (f16)(2.0f * sigm(acc));
}

__global__ void k_prep(const float* __restrict__ Wt, const float* __restrict__ W1,
                       f16* __restrict__ WtT, f16* __restrict__ W1T) {
    const int SZ = 3 * HD * HD;
    int id = blockIdx.x * 256 + threadIdx.x;
    if (id < SZ) {
        int t = id / (HD * HD), rem = id % (HD * HD);
        int n = rem / HD, k = rem % HD;
        WtT[id] = (f16)Wt[t * HD * HD + k * HD + n];
    } else if (id < SZ + 2 * HD * HD) {
        int rem = id - SZ;
        int n = rem / (2 * HD), k = rem % (2 * HD);
        W1T[rem] = (f16)W1[k * HD + n];
    }
}

// Wcat [512 rows j][256 k]
__global__ void k_prepW(const float* __restrict__ Wih, const float* __restrict__ Whh,
                        f16* __restrict__ Wcat) {
    int id = blockIdx.x * 256 + threadIdx.x;
    if (id < 512 * 256) {
        int j = id >> 8, k = id & 255;
        float v;
        if (j < 256)      v = (k < 128) ? Wih[j * 128 + k] : Whh[j * 128 + (k - 128)];
        else if (j < 384) v = (k < 128) ? Wih[j * 128 + k] : 0.0f;
        else              v = (k < 128) ? 0.0f : Whh[(j - 128) * 128 + (k - 128)];
        Wcat[id] = (f16)v;
    }
}

__global__ void k_init(const int* __restrict__ xidx, const float* __restrict__ sel,
                       const float* __restrict__ emb, f16* __restrict__ h, int N) {
    int id = blockIdx.x * 256 + threadIdx.x;
    if (id < N * HD) {
        int n = id >> 7, j = id & 127;
        float v = (j < EMBD) ? emb[(size_t)xidx[n] * EMBD + j]
                             : sel[(size_t)n * SELD + (j - EMBD)];
        h[id] = (f16)v;
    }
}

// ---------------- per-iteration kernel A: gather + message matmul ----------------
// (unchanged from round 12: 16 rows/block, 512 thr, dual-row gather,
//  type-sorted CSR + prefix-subtract packed-f16 accumulation)
__launch_bounds__(512, 4)
__global__ void k_agg(const int4* __restrict__ rp4, const int2* __restrict__ e2,
                      const f16* __restrict__ h_in, const f16* __restrict__ gb,
                      const f16* __restrict__ WtT, const float* __restrict__ bt,
                      const float4* __restrict__ cntp, f16* __restrict__ agg, int N) {
    __shared__ f16 S[3 * 16 * 136];
    __shared__ f16 aggL[16 * 136];

    int tid = threadIdx.x;
    int wave = tid >> 6, lane = tid & 63;
    int quad = lane >> 4, m = lane & 15;
    int half = lane >> 5, hl = lane & 31;
    int d0 = blockIdx.x * 16;

    // ---- P1: dual-row gather
    {
        int lrow = wave + half * 8;
        int grow = d0 + lrow;
        bool valid = grow < N;
        int4 r4 = rp4[min(grow, N - 1)];
        int es = r4.x, b1 = r4.y, b2 = r4.z, ee = r4.w;
        if (!valid) ee = es;
        int dg = ee - es;
        int dmax = max(dg, __shfl_xor(dg, 32));
        int nb = (__builtin_amdgcn_readfirstlane(dmax) + 7) >> 3;
        int co = hl * 4;  // 4 f16 cols per lane

        const f16x4 zf = {0, 0, 0, 0};
        f16x4 accA = zf, accB = zf, accC = zf;
        for (int b = 0; b < nb; ++b) {
            int e0 = es + b * 8;
            int2 ev[8];
            #pragma unroll
            for (int j = 0; j < 8; ++j) {
                int idx = max(min(e0 + j, ee - 1), 0);
                ev[j] = e2[idx];
            }
            f16x4 hv[8], gv[8];
            #pragma unroll
            for (int j = 0; j < 8; ++j) {
                hv[j] = *(const f16x4*)(h_in + (size_t)ev[j].x * HD + co);
                gv[j] = *(const f16x4*)(gb + (size_t)ev[j].y * HD + co);
            }
            #pragma unroll
            for (int j = 0; j < 8; ++j) {
                int eidx = e0 + j;
                f16x4 g0 = (eidx < ee) ? gv[j] : zf;   // active mask
                accA += hv[j] * g0;                     // v_pk_fma x2
                f16x4 gB = (eidx >= b1) ? g0 : zf;
                accB += hv[j] * gB;
                f16x4 gC = (eidx >= b2) ? g0 : zf;
                accC += hv[j] * gC;
            }
        }
        f16x4 s0 = accA - accB;   // type-0 sum
        f16x4 s1 = accB - accC;   // type-1 sum
        *(f16x4*)(S + (0 * 16 + lrow) * 136 + co) = s0;
        *(f16x4*)(S + (1 * 16 + lrow) * 136 + co) = s1;
        *(f16x4*)(S + (2 * 16 + lrow) * 136 + co) = accC;
    }
    __syncthreads();

    // ---- P2: message matmul: wave w -> cols w*16..+15
    {
        int col = wave * 16 + m;
        f32x4 acc = {0.f, 0.f, 0.f, 0.f};
        #pragma unroll
        for (int t = 0; t < 3; ++t)
            #pragma unroll
            for (int c = 0; c < 4; ++c) {
                f16x8 a = *(const f16x8*)(S + (t * 16 + m) * 136 + c * 32 + quad * 8);
                f16x8 b = *(const f16x8*)(WtT + ((size_t)t * HD + col) * HD + c * 32 + quad * 8);
                acc = __builtin_amdgcn_mfma_f32_16x16x32_f16(a, b, acc, 0, 0, 0);
            }
        float bt0 = bt[col], bt1 = bt[HD + col], bt2 = bt[2 * HD + col];
        #pragma unroll
        for (int r = 0; r < 4; ++r) {
            int lr = quad * 4 + r;
            int dd2 = min(d0 + lr, N - 1);
            float4 cp = cntp[dd2];
            float v = (acc[r] + cp.x * bt0 + cp.y * bt1 + cp.z * bt2) * cp.w;
            aggL[lr * 136 + col] = (f16)v;
        }
    }
    __syncthreads();

    // ---- coalesced copy-out: thread t -> row t>>5, 4 f16 at (t&31)*4
    {
        int row = tid >> 5, ch = tid & 31;
        if (d0 + row < N) {
            f16x4 v = *(const f16x4*)(aggL + row * 136 + ch * 4);
            *(f16x4*)(agg + (size_t)(d0 + row) * HD + ch * 4) = v;
        }
    }
}

// ---------------- per-iteration kernel B: GRU, persistent-B multi-tile ----------------
// Each block processes 4 consecutive 64-row tiles. B-fragments (Wcat) are
// loaded ONCE into registers (24 x f16x8 = 96 VGPRs) and reused across tiles
// -> 4x less L2 weight traffic than the per-64-row version. Accumulators run
// in two tau-pairs to keep live VGPRs ~160.
__launch_bounds__(512, 2)
__global__ void k_gru(const f16* __restrict__ agg, const f16* __restrict__ h_in,
                      const f16* __restrict__ Wcat, const float* __restrict__ bih,
                      const float* __restrict__ bhh, f16* __restrict__ h_out, int N) {
    __shared__ f16 AL[64 * 264];  // A tile, stride 264 (bank-spread)

    int tid = threadIdx.x;
    int wave = tid >> 6, lane = tid & 63;
    int quad = lane >> 4, m = lane & 15;
    int j = wave * 16 + m;  // output column within each gate (fixed per wave)

    // ---- persistent B fragments + biases (loaded once per block)
    f16x8 br[8], bz[8], bn[8];
    #pragma unroll
    for (int c = 0; c < 8; ++c) {
        br[c] = *(const f16x8*)(Wcat + (size_t)j * 256 + c * 32 + quad * 8);
        bz[c] = *(const f16x8*)(Wcat + (size_t)(128 + j) * 256 + c * 32 + quad * 8);
        bn[c] = (c < 4)
            ? *(const f16x8*)(Wcat + (size_t)(256 + j) * 256 + c * 32 + quad * 8)
            : *(const f16x8*)(Wcat + (size_t)(384 + j) * 256 + c * 32 + quad * 8);
    }
    float b_r  = bih[j] + bhh[j];
    float b_z  = bih[HD + j] + bhh[HD + j];
    float b_in = bih[2 * HD + j];
    float b_hn = bhh[2 * HD + j];

    for (int t = 0; t < 4; ++t) {
        int d0 = blockIdx.x * 256 + t * 64;
        if (d0 >= N) break;  // uniform across block

        __syncthreads();  // previous tile's LDS reads done before restage

        // ---- stage A = [agg | h]
        {
            int rsub = tid >> 5;   // 0..15
            int ch = tid & 31;     // 0..31
            #pragma unroll
            for (int i = 0; i < 4; ++i) {
                int row = i * 16 + rsub;
                int grow = min(d0 + row, N - 1);
                f16x8 v = (ch < 16)
                    ? *(const f16x8*)(agg + (size_t)grow * HD + ch * 8)
                    : *(const f16x8*)(h_in + (size_t)grow * HD + (ch - 16) * 8);
                *(f16x8*)(AL + row * 264 + ch * 8) = v;
            }
        }
        __syncthreads();

        // ---- GEMM in two tau-pairs (keeps live accumulators at 32 VGPRs)
        float hp[4][4];
        #pragma unroll
        for (int tp = 0; tp < 2; ++tp) {
            f32x4 ar[2], az[2], an[2], ah[2];
            const f32x4 z4 = {0.f, 0.f, 0.f, 0.f};
            ar[0] = z4; ar[1] = z4; az[0] = z4; az[1] = z4;
            an[0] = z4; an[1] = z4; ah[0] = z4; ah[1] = z4;

            #pragma unroll
            for (int c = 0; c < 8; ++c) {
                #pragma unroll
                for (int t2 = 0; t2 < 2; ++t2) {
                    int tau = tp * 2 + t2;
                    f16x8 a = *(const f16x8*)(AL + (tau * 16 + m) * 264 + c * 32 + quad * 8);
                    ar[t2] = __builtin_amdgcn_mfma_f32_16x16x32_f16(a, br[c], ar[t2], 0, 0, 0);
                    az[t2] = __builtin_amdgcn_mfma_f32_16x16x32_f16(a, bz[c], az[t2], 0, 0, 0);
                    if (c < 4) an[t2] = __builtin_amdgcn_mfma_f32_16x16x32_f16(a, bn[c], an[t2], 0, 0, 0);
                    else       ah[t2] = __builtin_amdgcn_mfma_f32_16x16x32_f16(a, bn[c], ah[t2], 0, 0, 0);
                }
            }
            #pragma unroll
            for (int t2 = 0; t2 < 2; ++t2)
                #pragma unroll
                for (int r = 0; r < 4; ++r) {
                    int row = (tp * 2 + t2) * 16 + quad * 4 + r;
                    float hval = (float)AL[row * 264 + 128 + j];
                    float rr = sigm(ar[t2][r] + b_r);
                    float zz = sigm(az[t2][r] + b_z);
                    float nn = tanh_f(an[t2][r] + b_in + rr * (ah[t2][r] + b_hn));
                    hp[tp * 2 + t2][r] = (1.0f - zz) * nn + zz * hval;
                }
        }
        __syncthreads();  // all AL reads done before reuse as output staging

        #pragma unroll
        for (int tau = 0; tau < 4; ++tau)
            #pragma unroll
            for (int r = 0; r < 4; ++r)
                AL[(tau * 16 + quad * 4 + r) * 132 + j] = (f16)hp[tau][r];
        __syncthreads();

        // ---- coalesced copy-out
        {
            int rsub = tid >> 5, ch = tid & 31;
            #pragma unroll
            for (int i = 0; i < 4; ++i) {
                int row = i * 16 + rsub;
                if (d0 + row < N) {
                    f16x4 v = *(const f16x4*)(AL + row * 132 + ch * 4);
                    *(f16x4*)(h_out + (size_t)(d0 + row) * HD + ch * 4) = v;
                }
            }
        }
    }
}

// feats=[h|emb[x]|sel] (f16 frags) @ W1T (MFMA) -> relu -> @W2 + b2
__launch_bounds__(256)
__global__ void k_final(const f16* __restrict__ h_f, const int* __restrict__ xidx,
                        const float* __restrict__ sel, const float* __restrict__ emb,
                        const f16* __restrict__ W1T, const float* __restrict__ b1,
                        const float* __restrict__ W2, const float* __restrict__ b2,
                        float* __restrict__ out, int N) {
    __shared__ float red[4][16];
    int tid = threadIdx.x;
    int wave = tid >> 6, lane = tid & 63;
    int quad = lane >> 4, m = lane & 15;
    int row0 = blockIdx.x * 16;
    int arow = min(row0 + m, N - 1);
    int xi = xidx[arow];

    f16x8 fa[8];
    #pragma unroll
    for (int c = 0; c < 4; ++c)
        fa[c] = *(const f16x8*)(h_f + (size_t)arow * HD + c * 32 + quad * 8);
    #pragma unroll
    for (int c = 4; c < 7; ++c) {
        const float* ep = emb + (size_t)xi * EMBD + (c - 4) * 32 + quad * 8;
        #pragma unroll
        for (int jj = 0; jj < 8; ++jj) fa[c][jj] = (f16)ep[jj];
    }
    {
        const float* sp = sel + (size_t)arow * SELD + quad * 8;
        #pragma unroll
        for (int jj = 0; jj < 8; ++jj) fa[7][jj] = (f16)sp[jj];
    }

    f32x4 acc[2];
    const f32x4 z4 = {0.f, 0.f, 0.f, 0.f};
    acc[0] = z4; acc[1] = z4;
    #pragma unroll
    for (int s = 0; s < 2; ++s) {
        int c0 = (wave * 2 + s) * 16;
        #pragma unroll
        for (int c = 0; c < 8; ++c) {
            f16x8 b = *(const f16x8*)(W1T + (size_t)(c0 + m) * (2 * HD) + c * 32 + quad * 8);
            acc[s] = __builtin_amdgcn_mfma_f32_16x16x32_f16(fa[c], b, acc[s], 0, 0, 0);
        }
    }

    float psum[4] = {0.f, 0.f, 0.f, 0.f};
    #pragma unroll
    for (int s = 0; s < 2; ++s) {
        int col = (wave * 2 + s) * 16 + m;
        float b1v = b1[col], w2v = W2[col];
        #pragma unroll
        for (int r = 0; r < 4; ++r)
            psum[r] += fmaxf(acc[s][r] + b1v, 0.0f) * w2v;
    }
    #pragma unroll
    for (int off = 1; off < 16; off <<= 1)
        #pragma unroll
        for (int r = 0; r < 4; ++r) psum[r] += __shfl_xor(psum[r], off);

    if (m == 0) {
        #pragma unroll
        for (int r = 0; r < 4; ++r) red[wave][quad * 4 + r] = psum[r];
    }
    __syncthreads();
    if (tid < 16) {
        int row = row0 + tid;
        if (row < N) out[row] = red[0][tid] + red[1][tid] + red[2][tid] + red[3][tid] + b2[0];
    }
}

// ---------------- launcher ----------------

extern "C" void kernel_launch(void* const* d_in, const int* in_sizes, int n_in,
                              void* d_out, int out_size, void* d_ws, size_t ws_size,
                              hipStream_t stream) {
    const int*   xidx = (const int*)d_in[0];
    const float* sel  = (const float*)d_in[1];
    const int*   ei   = (const int*)d_in[2];
    const int*   et   = (const int*)d_in[3];
    const int*   ep   = (const int*)d_in[4];
    const float* emb  = (const float*)d_in[5];
    const float* pe   = (const float*)d_in[6];
    const float* Wg   = (const float*)d_in[7];
    const float* bg   = (const float*)d_in[8];
    const float* Wt   = (const float*)d_in[9];
    const float* bt   = (const float*)d_in[10];
    const float* Wih  = (const float*)d_in[11];
    const float* Whh  = (const float*)d_in[12];
    const float* bih  = (const float*)d_in[13];
    const float* bhh  = (const float*)d_in[14];
    const float* W1   = (const float*)d_in[15];
    const float* b1   = (const float*)d_in[16];
    const float* W2   = (const float*)d_in[17];
    const float* b2   = (const float*)d_in[18];

    const int N = in_sizes[0];
    const int E = in_sizes[3];
    const size_t NH = (size_t)N * HD;

    char* p = (char*)d_ws;
    f16*    hbf0  = (f16*)p;    p += NH * 2;
    f16*    hbf1  = (f16*)p;    p += NH * 2;
    f16*    aggb  = (f16*)p;    p += NH * 2;
    f16*    gb    = (f16*)p;    p += (size_t)NPOS * HD * 2;
    f16*    WtT   = (f16*)p;    p += 3 * HD * HD * 2;
    f16*    Wcat  = (f16*)p;    p += 512 * 256 * 2;
    f16*    W1T   = (f16*)p;    p += 2 * HD * HD * 2;
    float4* cntp  = (float4*)p; p += (size_t)N * 16;
    int4*   rp4   = (int4*)p;   p += (size_t)N * 16;
    int* cnt_t  = (int*)p; p += 3 * (size_t)N * 4;
    int* rp     = (int*)p; p += (size_t)N * 4;
    int* cur3   = (int*)p; p += 3 * (size_t)N * 4;
    int* bsum   = (int*)p; p += 1024 * 4;
    int2* e2    = (int2*)p;

    // ---- setup ----
    hipMemsetAsync(cnt_t, 0, 3 * (size_t)N * sizeof(int), stream);
    hipMemsetAsync(cur3, 0, 3 * (size_t)N * sizeof(int), stream);
    k_deg<<<(E + 255) / 256, 256, 0, stream>>>(ei, et, cnt_t, E, N);
    const int nb1 = (N + 1023) / 1024;
    k_scan1<<<nb1, 1024, 0, stream>>>(cnt_t, rp, bsum, N);
    k_scan2<<<1, 1024, 0, stream>>>(bsum, nb1);
    k_scan3<<<(N + 255) / 256, 256, 0, stream>>>(rp, bsum, cnt_t, cntp, rp4, N);
    k_fill<<<(E + 255) / 256, 256, 0, stream>>>(ei, et, ep, rp4, cur3, e2, E, N);
    k_gate<<<NPOS, HD, 0, stream>>>(pe, Wg, bg, gb);
    k_prep<<<(3 * HD * HD + 2 * HD * HD + 255) / 256, 256, 0, stream>>>(Wt, W1, WtT, W1T);
    k_prepW<<<512, 256, 0, stream>>>(Wih, Whh, Wcat);
    k_init<<<(N * HD + 255) / 256, 256, 0, stream>>>(xidx, sel, emb, hbf0, N);

    const int gA = (N + 15) / 16;
    const int gG = (N + 255) / 256;
    const f16* hin = hbf0;
    f16* hout = hbf1;
    for (int it = 0; it < GITERS; ++it) {
        k_agg<<<gA, 512, 0, stream>>>(rp4, e2, hin, gb, WtT, bt, cntp, aggb, N);
        k_gru<<<gG, 512, 0, stream>>>(aggb, hin, Wcat, bih, bhh, hout, N);
        const f16* tmp = hout;
        hout = (f16*)hin;
        hin = tmp;
    }

    const int gF = (N + 15) / 16;
    k_final<<<gF, 256, 0, stream>>>(hin, xidx, sel, emb, W1T, b1, W2, b2, (float*)d_out, N);
}

// Round 15
// 1207.548 us; speedup vs baseline: 1.1663x; 1.0885x over previous
//
#include <hip/hip_runtime.h>
#include <cstdint>
#include <cstddef>

#define HD 128
#define EMBD 96
#define SELD 32
#define PD 64
#define NPOS 513
#define GITERS 6

typedef _Float16 f16;
typedef __attribute__((ext_vector_type(8))) _Float16 f16x8;
typedef __attribute__((ext_vector_type(4))) _Float16 f16x4;
typedef __attribute__((ext_vector_type(2))) _Float16 f16x2;
typedef __attribute__((ext_vector_type(4))) float f32x4;

__device__ __forceinline__ float sigm(float x) {
    return __builtin_amdgcn_rcpf(1.0f + __expf(-x));
}
__device__ __forceinline__ float tanh_f(float x) {
    return 2.0f * __builtin_amdgcn_rcpf(1.0f + __expf(-2.0f * x)) - 1.0f;
}

// ---------------- setup kernels ----------------

__global__ void k_deg(const int* __restrict__ ei, const int* __restrict__ et,
                      int* __restrict__ cnt_t, int E, int N) {
    int e = blockIdx.x * 256 + threadIdx.x;
    if (e < E) {
        int d = ei[E + e];
        atomicAdd(&cnt_t[(size_t)et[e] * N + d], 1);
    }
}

__launch_bounds__(1024)
__global__ void k_scan1(const int* __restrict__ cnt_t, int* __restrict__ rp,
                        int* __restrict__ bsum, int N) {
    __shared__ int sc[1024];
    int t = threadIdx.x;
    int i = blockIdx.x * 1024 + t;
    int v = 0;
    if (i < N)
        v = cnt_t[i] + cnt_t[(size_t)N + i] + cnt_t[2 * (size_t)N + i];
    sc[t] = v;
    __syncthreads();
    for (int off = 1; off < 1024; off <<= 1) {
        int u = (t >= off) ? sc[t - off] : 0;
        __syncthreads();
        sc[t] += u;
        __syncthreads();
    }
    if (i < N) rp[i] = sc[t] - v;
    if (t == 1023) bsum[blockIdx.x] = sc[t];
}

__launch_bounds__(1024)
__global__ void k_scan2(int* __restrict__ bsum, int nb) {
    __shared__ int sc[1024];
    int t = threadIdx.x;
    int v = (t < nb) ? bsum[t] : 0;
    sc[t] = v;
    __syncthreads();
    for (int off = 1; off < 1024; off <<= 1) {
        int u = (t >= off) ? sc[t - off] : 0;
        __syncthreads();
        sc[t] += u;
        __syncthreads();
    }
    if (t < nb) bsum[t] = sc[t] - v;
}

__global__ void k_scan3(const int* __restrict__ rp, const int* __restrict__ bsum,
                        const int* __restrict__ cnt_t, float4* __restrict__ cntp,
                        int4* __restrict__ rp4, int N) {
    int i = blockIdx.x * 256 + threadIdx.x;
    if (i < N) {
        int start = rp[i] + bsum[i >> 10];
        int c0 = cnt_t[i];
        int c1 = cnt_t[(size_t)N + i];
        int c2 = cnt_t[2 * (size_t)N + i];
        rp4[i] = make_int4(start, start + c0, start + c0 + c1, start + c0 + c1 + c2);
        float4 v;
        v.x = (float)c0; v.y = (float)c1; v.z = (float)c2;
        v.w = 1.0f / fmaxf((float)(c0 + c1 + c2), 1.0f);
        cntp[i] = v;
    }
}

__global__ void k_fill(const int* __restrict__ ei, const int* __restrict__ et,
                       const int* __restrict__ ep, const int4* __restrict__ rp4,
                       int* __restrict__ cur3, int2* __restrict__ e2, int E, int N) {
    int e = blockIdx.x * 256 + threadIdx.x;
    if (e < E) {
        int d = ei[E + e];
        int t = et[e];
        int4 r4 = rp4[d];
        int base = (t == 0) ? r4.x : ((t == 1) ? r4.y : r4.z);
        int pos = atomicAdd(&cur3[(size_t)t * N + d], 1);
        e2[base + pos] = make_int2(ei[e], ep[e]);
    }
}

__global__ void k_gate(const float* __restrict__ pe, const float* __restrict__ Wg,
                       const float* __restrict__ bg, f16* __restrict__ gb) {
    int p = blockIdx.x;
    int j = threadIdx.x;
    float acc = bg[j];
    #pragma unroll 8
    for (int k = 0; k < PD; ++k) acc += pe[p * PD + k] * Wg[k * HD + j];
    gb[p * HD + j] = (f16)(2.0f * sigm(acc));
}

__global__ void k_prep(const float* __restrict__ Wt, const float* __restrict__ W1,
                       f16* __restrict__ WtT, f16* __restrict__ W1T) {
    const int SZ = 3 * HD * HD;
    int id = blockIdx.x * 256 + threadIdx.x;
    if (id < SZ) {
        int t = id / (HD * HD), rem = id % (HD * HD);
        int n = rem / HD, k = rem % HD;
        WtT[id] = (f16)Wt[t * HD * HD + k * HD + n];
    } else if (id < SZ + 2 * HD * HD) {
        int rem = id - SZ;
        int n = rem / (2 * HD), k = rem % (2 * HD);
        W1T[rem] = (f16)W1[k * HD + n];
    }
}

// Wcat [512 rows j][256 k]
__global__ void k_prepW(const float* __restrict__ Wih, const float* __restrict__ Whh,
                        f16* __restrict__ Wcat) {
    int id = blockIdx.x * 256 + threadIdx.x;
    if (id < 512 * 256) {
        int j = id >> 8, k = id & 255;
        float v;
        if (j < 256)      v = (k < 128) ? Wih[j * 128 + k] : Whh[j * 128 + (k - 128)];
        else if (j < 384) v = (k < 128) ? Wih[j * 128 + k] : 0.0f;
        else              v = (k < 128) ? 0.0f : Whh[(j - 128) * 128 + (k - 128)];
        Wcat[id] = (f16)v;
    }
}

__global__ void k_init(const int* __restrict__ xidx, const float* __restrict__ sel,
                       const float* __restrict__ emb, f16* __restrict__ h, int N) {
    int id = blockIdx.x * 256 + threadIdx.x;
    if (id < N * HD) {
        int n = id >> 7, j = id & 127;
        float v = (j < EMBD) ? emb[(size_t)xidx[n] * EMBD + j]
                             : sel[(size_t)n * SELD + (j - EMBD)];
        h[id] = (f16)v;
    }
}

// ---------------- per-iteration kernel A: gather + message matmul ----------------
// 16 rows/block, 256 thr (4 waves). Each wave gathers FOUR rows at once:
// lane quarter qw owns row wave*4+qw, 16 lanes x f16x8 = 256B row. One h/gate
// VMEM instruction serves 4 edges (vs 2 in the dual-row version) -> gather
// request count halves. Batch-4 keeps 16 independent loads in flight/wave
// while minimizing round-up waste and VGPR pressure.
__launch_bounds__(256, 6)
__global__ void k_agg(const int4* __restrict__ rp4, const int2* __restrict__ e2,
                      const f16* __restrict__ h_in, const f16* __restrict__ gb,
                      const f16* __restrict__ WtT, const float* __restrict__ bt,
                      const float4* __restrict__ cntp, f16* __restrict__ agg, int N) {
    __shared__ f16 S[3 * 16 * 136];
    __shared__ f16 aggL[16 * 136];

    int tid = threadIdx.x;
    int wave = tid >> 6, lane = tid & 63;
    int quad = lane >> 4, m = lane & 15;
    int qw = lane >> 4, ql = lane & 15;
    int d0 = blockIdx.x * 16;

    // ---- P1: quad-row gather
    {
        int lrow = wave * 4 + qw;
        int grow = d0 + lrow;
        bool valid = grow < N;
        int4 r4 = rp4[min(grow, N - 1)];
        int es = r4.x, b1 = r4.y, b2 = r4.z, ee = r4.w;
        if (!valid) ee = es;
        int dg = ee - es;
        int t1 = max(dg, __shfl_xor(dg, 16));
        int t2 = max(t1, __shfl_xor(t1, 32));
        int nb = (__builtin_amdgcn_readfirstlane(t2) + 3) >> 2;
        int co = ql * 8;  // 8 f16 per lane (16 B); 16 lanes cover the 256B row

        const f16x8 zf = {0, 0, 0, 0, 0, 0, 0, 0};
        f16x8 accA = zf, accB = zf, accC = zf;
        for (int b = 0; b < nb; ++b) {
            int e0 = es + b * 4;
            int2 ev[4];
            #pragma unroll
            for (int j = 0; j < 4; ++j) {
                int idx = max(min(e0 + j, ee - 1), 0);
                ev[j] = e2[idx];
            }
            f16x8 hv[4], gv[4];
            #pragma unroll
            for (int j = 0; j < 4; ++j) {
                hv[j] = *(const f16x8*)(h_in + (size_t)ev[j].x * HD + co);
                gv[j] = *(const f16x8*)(gb + (size_t)ev[j].y * HD + co);
            }
            #pragma unroll
            for (int j = 0; j < 4; ++j) {
                int eidx = e0 + j;
                f16x8 g0 = (eidx < ee) ? gv[j] : zf;   // active mask
                accA += hv[j] * g0;                     // v_pk_fma
                f16x8 gB = (eidx >= b1) ? g0 : zf;
                accB += hv[j] * gB;
                f16x8 gC = (eidx >= b2) ? g0 : zf;
                accC += hv[j] * gC;
            }
        }
        f16x8 s0 = accA - accB;   // type-0 sum
        f16x8 s1 = accB - accC;   // type-1 sum
        *(f16x8*)(S + (0 * 16 + lrow) * 136 + co) = s0;
        *(f16x8*)(S + (1 * 16 + lrow) * 136 + co) = s1;
        *(f16x8*)(S + (2 * 16 + lrow) * 136 + co) = accC;
    }
    __syncthreads();

    // ---- P2: message matmul: wave w -> col-groups {w, w+4}
    #pragma unroll
    for (int s = 0; s < 2; ++s) {
        int col = (wave + s * 4) * 16 + m;
        f32x4 acc = {0.f, 0.f, 0.f, 0.f};
        #pragma unroll
        for (int t = 0; t < 3; ++t)
            #pragma unroll
            for (int c = 0; c < 4; ++c) {
                f16x8 a = *(const f16x8*)(S + (t * 16 + m) * 136 + c * 32 + quad * 8);
                f16x8 b = *(const f16x8*)(WtT + ((size_t)t * HD + col) * HD + c * 32 + quad * 8);
                acc = __builtin_amdgcn_mfma_f32_16x16x32_f16(a, b, acc, 0, 0, 0);
            }
        float bt0 = bt[col], bt1 = bt[HD + col], bt2 = bt[2 * HD + col];
        #pragma unroll
        for (int r = 0; r < 4; ++r) {
            int lr = quad * 4 + r;
            int dd2 = min(d0 + lr, N - 1);
            float4 cp = cntp[dd2];
            float v = (acc[r] + cp.x * bt0 + cp.y * bt1 + cp.z * bt2) * cp.w;
            aggL[lr * 136 + col] = (f16)v;
        }
    }
    __syncthreads();

    // ---- coalesced copy-out: thread t -> row t>>4, f16x8 at (t&15)*8
    {
        int row = tid >> 4, ch = tid & 15;
        if (d0 + row < N) {
            f16x8 v = *(const f16x8*)(aggL + row * 136 + ch * 8);
            *(f16x8*)(agg + (size_t)(d0 + row) * HD + ch * 8) = v;
        }
    }
}

// ---------------- per-iteration kernel B: GRU, persistent-B multi-tile ----------------
// (unchanged from round 14)
__launch_bounds__(512, 2)
__global__ void k_gru(const f16* __restrict__ agg, const f16* __restrict__ h_in,
                      const f16* __restrict__ Wcat, const float* __restrict__ bih,
                      const float* __restrict__ bhh, f16* __restrict__ h_out, int N) {
    __shared__ f16 AL[64 * 264];  // A tile, stride 264 (bank-spread)

    int tid = threadIdx.x;
    int wave = tid >> 6, lane = tid & 63;
    int quad = lane >> 4, m = lane & 15;
    int j = wave * 16 + m;

    f16x8 br[8], bz[8], bn[8];
    #pragma unroll
    for (int c = 0; c < 8; ++c) {
        br[c] = *(const f16x8*)(Wcat + (size_t)j * 256 + c * 32 + quad * 8);
        bz[c] = *(const f16x8*)(Wcat + (size_t)(128 + j) * 256 + c * 32 + quad * 8);
        bn[c] = (c < 4)
            ? *(const f16x8*)(Wcat + (size_t)(256 + j) * 256 + c * 32 + quad * 8)
            : *(const f16x8*)(Wcat + (size_t)(384 + j) * 256 + c * 32 + quad * 8);
    }
    float b_r  = bih[j] + bhh[j];
    float b_z  = bih[HD + j] + bhh[HD + j];
    float b_in = bih[2 * HD + j];
    float b_hn = bhh[2 * HD + j];

    for (int t = 0; t < 4; ++t) {
        int d0 = blockIdx.x * 256 + t * 64;
        if (d0 >= N) break;

        __syncthreads();

        {
            int rsub = tid >> 5;
            int ch = tid & 31;
            #pragma unroll
            for (int i = 0; i < 4; ++i) {
                int row = i * 16 + rsub;
                int grow = min(d0 + row, N - 1);
                f16x8 v = (ch < 16)
                    ? *(const f16x8*)(agg + (size_t)grow * HD + ch * 8)
                    : *(const f16x8*)(h_in + (size_t)grow * HD + (ch - 16) * 8);
                *(f16x8*)(AL + row * 264 + ch * 8) = v;
            }
        }
        __syncthreads();

        float hp[4][4];
        #pragma unroll
        for (int tp = 0; tp < 2; ++tp) {
            f32x4 ar[2], az[2], an[2], ah[2];
            const f32x4 z4 = {0.f, 0.f, 0.f, 0.f};
            ar[0] = z4; ar[1] = z4; az[0] = z4; az[1] = z4;
            an[0] = z4; an[1] = z4; ah[0] = z4; ah[1] = z4;

            #pragma unroll
            for (int c = 0; c < 8; ++c) {
                #pragma unroll
                for (int t2 = 0; t2 < 2; ++t2) {
                    int tau = tp * 2 + t2;
                    f16x8 a = *(const f16x8*)(AL + (tau * 16 + m) * 264 + c * 32 + quad * 8);
                    ar[t2] = __builtin_amdgcn_mfma_f32_16x16x32_f16(a, br[c], ar[t2], 0, 0, 0);
                    az[t2] = __builtin_amdgcn_mfma_f32_16x16x32_f16(a, bz[c], az[t2], 0, 0, 0);
                    if (c < 4) an[t2] = __builtin_amdgcn_mfma_f32_16x16x32_f16(a, bn[c], an[t2], 0, 0, 0);
                    else       ah[t2] = __builtin_amdgcn_mfma_f32_16x16x32_f16(a, bn[c], ah[t2], 0, 0, 0);
                }
            }
            #pragma unroll
            for (int t2 = 0; t2 < 2; ++t2)
                #pragma unroll
                for (int r = 0; r < 4; ++r) {
                    int row = (tp * 2 + t2) * 16 + quad * 4 + r;
                    float hval = (float)AL[row * 264 + 128 + j];
                    float rr = sigm(ar[t2][r] + b_r);
                    float zz = sigm(az[t2][r] + b_z);
                    float nn = tanh_f(an[t2][r] + b_in + rr * (ah[t2][r] + b_hn));
                    hp[tp * 2 + t2][r] = (1.0f - zz) * nn + zz * hval;
                }
        }
        __syncthreads();

        #pragma unroll
        for (int tau = 0; tau < 4; ++tau)
            #pragma unroll
            for (int r = 0; r < 4; ++r)
                AL[(tau * 16 + quad * 4 + r) * 132 + j] = (f16)hp[tau][r];
        __syncthreads();

        {
            int rsub = tid >> 5, ch = tid & 31;
            #pragma unroll
            for (int i = 0; i < 4; ++i) {
                int row = i * 16 + rsub;
                if (d0 + row < N) {
                    f16x4 v = *(const f16x4*)(AL + row * 132 + ch * 4);
                    *(f16x4*)(h_out + (size_t)(d0 + row) * HD + ch * 4) = v;
                }
            }
        }
    }
}

// feats=[h|emb[x]|sel] (f16 frags) @ W1T (MFMA) -> relu -> @W2 + b2
__launch_bounds__(256)
__global__ void k_final(const f16* __restrict__ h_f, const int* __restrict__ xidx,
                        const float* __restrict__ sel, const float* __restrict__ emb,
                        const f16* __restrict__ W1T, const float* __restrict__ b1,
                        const float* __restrict__ W2, const float* __restrict__ b2,
                        float* __restrict__ out, int N) {
    __shared__ float red[4][16];
    int tid = threadIdx.x;
    int wave = tid >> 6, lane = tid & 63;
    int quad = lane >> 4, m = lane & 15;
    int row0 = blockIdx.x * 16;
    int arow = min(row0 + m, N - 1);
    int xi = xidx[arow];

    f16x8 fa[8];
    #pragma unroll
    for (int c = 0; c < 4; ++c)
        fa[c] = *(const f16x8*)(h_f + (size_t)arow * HD + c * 32 + quad * 8);
    #pragma unroll
    for (int c = 4; c < 7; ++c) {
        const float* ep = emb + (size_t)xi * EMBD + (c - 4) * 32 + quad * 8;
        #pragma unroll
        for (int jj = 0; jj < 8; ++jj) fa[c][jj] = (f16)ep[jj];
    }
    {
        const float* sp = sel + (size_t)arow * SELD + quad * 8;
        #pragma unroll
        for (int jj = 0; jj < 8; ++jj) fa[7][jj] = (f16)sp[jj];
    }

    f32x4 acc[2];
    const f32x4 z4 = {0.f, 0.f, 0.f, 0.f};
    acc[0] = z4; acc[1] = z4;
    #pragma unroll
    for (int s = 0; s < 2; ++s) {
        int c0 = (wave * 2 + s) * 16;
        #pragma unroll
        for (int c = 0; c < 8; ++c) {
            f16x8 b = *(const f16x8*)(W1T + (size_t)(c0 + m) * (2 * HD) + c * 32 + quad * 8);
            acc[s] = __builtin_amdgcn_mfma_f32_16x16x32_f16(fa[c], b, acc[s], 0, 0, 0);
        }
    }

    float psum[4] = {0.f, 0.f, 0.f, 0.f};
    #pragma unroll
    for (int s = 0; s < 2; ++s) {
        int col = (wave * 2 + s) * 16 + m;
        float b1v = b1[col], w2v = W2[col];
        #pragma unroll
        for (int r = 0; r < 4; ++r)
            psum[r] += fmaxf(acc[s][r] + b1v, 0.0f) * w2v;
    }
    #pragma unroll
    for (int off = 1; off < 16; off <<= 1)
        #pragma unroll
        for (int r = 0; r < 4; ++r) psum[r] += __shfl_xor(psum[r], off);

    if (m == 0) {
        #pragma unroll
        for (int r = 0; r < 4; ++r) red[wave][quad * 4 + r] = psum[r];
    }
    __syncthreads();
    if (tid < 16) {
        int row = row0 + tid;
        if (row < N) out[row] = red[0][tid] + red[1][tid] + red[2][tid] + red[3][tid] + b2[0];
    }
}

// ---------------- launcher ----------------

extern "C" void kernel_launch(void* const* d_in, const int* in_sizes, int n_in,
                              void* d_out, int out_size, void* d_ws, size_t ws_size,
                              hipStream_t stream) {
    const int*   xidx = (const int*)d_in[0];
    const float* sel  = (const float*)d_in[1];
    const int*   ei   = (const int*)d_in[2];
    const int*   et   = (const int*)d_in[3];
    const int*   ep   = (const int*)d_in[4];
    const float* emb  = (const float*)d_in[5];
    const float* pe   = (const float*)d_in[6];
    const float* Wg   = (const float*)d_in[7];
    const float* bg   = (const float*)d_in[8];
    const float* Wt   = (const float*)d_in[9];
    const float* bt   = (const float*)d_in[10];
    const float* Wih  = (const float*)d_in[11];
    const float* Whh  = (const float*)d_in[12];
    const float* bih  = (const float*)d_in[13];
    const float* bhh  = (const float*)d_in[14];
    const float* W1   = (const float*)d_in[15];
    const float* b1   = (const float*)d_in[16];
    const float* W2   = (const float*)d_in[17];
    const float* b2   = (const float*)d_in[18];

    const int N = in_sizes[0];
    const int E = in_sizes[3];
    const size_t NH = (size_t)N * HD;

    char* p = (char*)d_ws;
    f16*    hbf0  = (f16*)p;    p += NH * 2;
    f16*    hbf1  = (f16*)p;    p += NH * 2;
    f16*    aggb  = (f16*)p;    p += NH * 2;
    f16*    gb    = (f16*)p;    p += (size_t)NPOS * HD * 2;
    f16*    WtT   = (f16*)p;    p += 3 * HD * HD * 2;
    f16*    Wcat  = (f16*)p;    p += 512 * 256 * 2;
    f16*    W1T   = (f16*)p;    p += 2 * HD * HD * 2;
    float4* cntp  = (float4*)p; p += (size_t)N * 16;
    int4*   rp4   = (int4*)p;   p += (size_t)N * 16;
    int* cnt_t  = (int*)p; p += 3 * (size_t)N * 4;
    int* rp     = (int*)p; p += (size_t)N * 4;
    int* cur3   = (int*)p; p += 3 * (size_t)N * 4;
    int* bsum   = (int*)p; p += 1024 * 4;
    int2* e2    = (int2*)p;

    // ---- setup ----
    hipMemsetAsync(cnt_t, 0, 3 * (size_t)N * sizeof(int), stream);
    hipMemsetAsync(cur3, 0, 3 * (size_t)N * sizeof(int), stream);
    k_deg<<<(E + 255) / 256, 256, 0, stream>>>(ei, et, cnt_t, E, N);
    const int nb1 = (N + 1023) / 1024;
    k_scan1<<<nb1, 1024, 0, stream>>>(cnt_t, rp, bsum, N);
    k_scan2<<<1, 1024, 0, stream>>>(bsum, nb1);
    k_scan3<<<(N + 255) / 256, 256, 0, stream>>>(rp, bsum, cnt_t, cntp, rp4, N);
    k_fill<<<(E + 255) / 256, 256, 0, stream>>>(ei, et, ep, rp4, cur3, e2, E, N);
    k_gate<<<NPOS, HD, 0, stream>>>(pe, Wg, bg, gb);
    k_prep<<<(3 * HD * HD + 2 * HD * HD + 255) / 256, 256, 0, stream>>>(Wt, W1, WtT, W1T);
    k_prepW<<<512, 256, 0, stream>>>(Wih, Whh, Wcat);
    k_init<<<(N * HD + 255) / 256, 256, 0, stream>>>(xidx, sel, emb, hbf0, N);

    const int gA = (N + 15) / 16;
    const int gG = (N + 255) / 256;
    const f16* hin = hbf0;
    f16* hout = hbf1;
    for (int it = 0; it < GITERS; ++it) {
        k_agg<<<gA, 256, 0, stream>>>(rp4, e2, hin, gb, WtT, bt, cntp, aggb, N);
        k_gru<<<gG, 512, 0, stream>>>(aggb, hin, Wcat, bih, bhh, hout, N);
        const f16* tmp = hout;
        hout = (f16*)hin;
        hin = tmp;
    }

    const int gF = (N + 15) / 16;
    k_final<<<gF, 256, 0, stream>>>(hin, xidx, sel, emb, W1T, b1, W2, b2, (float*)d_out, N);
}